// Round 14
// baseline (576.202 us; speedup 1.0000x reference)
//
#include <hip/hip_runtime.h>

// HNM discriminative loss, MI355X — R17 (DIAGNOSTIC).
// predict (4,32,512,1024) f32, target (4,512,1024) i32 -> scalar f32.
// R17: 11 rounds oscillating 436-444; 5 k_var / 3 k_accum structures all
// within +-5% at ~155/~115us, each ~2.5x over every micro-model; zero
// counter rows for my code since R6 (everything hides under the 159us
// harness ws-poison fill). This round BUYS COUNTERS: both hot kernels run
// their main loop TWICE (results *0.5 -> still correct), lifting them to
// ~220/~310us = above the fill = full counter rows. asm memory clobber
// between sweeps prevents load-CSE (restrict + identical addresses).
// Sweep 2 reads pred L3-warm -> dur ratio vs 1x is a warm/cold probe.
// Everything else byte-identical to R16 (the timed fallback).

#define K_CLS 19
#define C_CH 32
#define HW_SHIFT 19            // H*W = 512*1024 = 2^19
#define HW_SIZE (1 << HW_SHIFT)
#define EPSF 1e-12f
#define THEA_F 0.5f
#define TWO_DELTA 3.0f
#define MIN_PIX 20.0f

// ---- ws float layout ------------------------------------------------------
#define OFF_PSUM 0                       // [ch][64 slots][20] = 40960
#define OFF_PCNT 40960                   // [64 slots][20] = 1280
#define OFF_RED  42240                   // 608 sums + 19 counts (pad 640)
#define OFF_VRED 42880                   // 38 reduced sq/pos (pad 64)
#define OFF_VPART 42944                  // [1024 blk][64]: 19 sq + 19 pos
#define OFF_MAP  108480                  // u8 class map: 2MB = 524288 floats
#define WS_FLOATS (OFF_MAP + 524288)

__device__ __forceinline__ void atomAddF(float* p, float v) {
  unsafeAtomicAdd(p, v);       // cold paths only
}

__device__ __forceinline__ float bperm(float v, int byteidx) {
  return __int_as_float(__builtin_amdgcn_ds_bpermute(byteidx, __float_as_int(v)));
}

// ---- Pack: tgt int32 -> u8 class map (2MB). ~3us. -------------------------
__global__ __launch_bounds__(256) void k_pack(
    const int* __restrict__ tgt, float* __restrict__ ws)
{
  const int i = blockIdx.x * 256 + threadIdx.x;   // word index, 4 px each
  const int4 c = *reinterpret_cast<const int4*>(tgt + (size_t)i * 4);
  const unsigned u = (unsigned)(c.x & 255) | ((unsigned)(c.y & 255) << 8)
                   | ((unsigned)(c.z & 255) << 16) | ((unsigned)(c.w & 255) << 24);
  reinterpret_cast<unsigned*>(ws + OFF_MAP)[i] = u;
}

// ---- Pass 1 (2-sweep diagnostic): bank-per-lane histogram -----------------
__global__ __launch_bounds__(256) void k_accum(
    const float* __restrict__ pred, float* __restrict__ ws)
{
  __shared__ float sA[4][K_CLS][64];            // 19456 B -> 8 blocks/CU
  __shared__ float s_w[4][20];
  const int t = threadIdx.x;
  const int w = t >> 6;
  const int lane = t & 63;
  const unsigned* umap = reinterpret_cast<const unsigned*>(ws + OFF_MAP);
  float* colA = &sA[w][0][lane];                // colA[k<<6] = bin k, bank l%32
#pragma unroll
  for (int k = 0; k < K_CLS; ++k) colA[k << 6] = 0.f;

  if (blockIdx.x < 2048) {
    const int plane = blockIdx.x >> 4;       // 0..127
    const int slab  = blockIdx.x & 15;       // 0..15
    const int n_idx = plane >> 5;
    const int ch    = plane & 31;
    const float* pbase = pred + (((size_t)plane) << HW_SHIFT) + ((size_t)slab << 15);
    const int mbase = ((n_idx << HW_SHIFT) + (slab << 15)) >> 2;

    auto sweepA = [&]() {
      float4 vA = *reinterpret_cast<const float4*>(pbase + t * 4);
      unsigned mA = umap[mbase + t];
#pragma unroll 1
      for (int it = 0; it < 32; ++it) {
        float4 vB; unsigned mB;
        if (it + 1 < 32) {
          vB = *reinterpret_cast<const float4*>(pbase + (it + 1) * 1024 + t * 4);
          mB = umap[mbase + (it + 1) * 256 + t];
        }
        const unsigned b0 = mA & 255u, b1 = (mA >> 8) & 255u;
        const unsigned b2 = (mA >> 16) & 255u, b3 = mA >> 24;
        const int   k0 = min(b0, 18u), k1 = min(b1, 18u);
        const int   k2 = min(b2, 18u), k3 = min(b3, 18u);
        const float v0 = (b0 < K_CLS) ? vA.x : 0.f;
        const float v1 = (b1 < K_CLS) ? vA.y : 0.f;
        const float v2 = (b2 < K_CLS) ? vA.z : 0.f;
        const float v3 = (b3 < K_CLS) ? vA.w : 0.f;
        colA[k0 << 6] += v0;
        colA[k1 << 6] += v1;
        colA[k2 << 6] += v2;
        colA[k3 << 6] += v3;
        vA = vB; mA = mB;
      }
    };
    sweepA();
    asm volatile("" ::: "memory");   // forbid load-CSE across sweeps
    sweepA();

    float acc[K_CLS];
#pragma unroll
    for (int k = 0; k < K_CLS; ++k) acc[k] = colA[k << 6];
#pragma unroll
    for (int k = 0; k < K_CLS; ++k) {
      float s = acc[k];
#pragma unroll
      for (int m = 1; m < 64; m <<= 1) s += __shfl_xor(s, m, 64);
      acc[k] = s;
    }
#pragma unroll
    for (int k = 0; k < K_CLS; ++k)
      if (lane == k) s_w[w][k] = acc[k];
    __syncthreads();
    if (t < K_CLS) {
      const int slot = n_idx * 16 + slab;
      ws[OFF_PSUM + ch * (64 * 20) + slot * 20 + t] =
          0.5f * (s_w[0][t] + s_w[1][t] + s_w[2][t] + s_w[3][t]);
    }
  } else {
    const int idx = blockIdx.x - 2048;       // 0..63
    const int mbase = idx << 13;             // (idx*32768)/4

    auto sweepC = [&]() {
#pragma unroll 1
      for (int it = 0; it < 32; ++it) {
        const unsigned m = umap[mbase + it * 256 + t];
        const unsigned b0 = m & 255u, b1 = (m >> 8) & 255u;
        const unsigned b2 = (m >> 16) & 255u, b3 = m >> 24;
        colA[min(b0, 18u) << 6] += (b0 < K_CLS) ? 1.f : 0.f;
        colA[min(b1, 18u) << 6] += (b1 < K_CLS) ? 1.f : 0.f;
        colA[min(b2, 18u) << 6] += (b2 < K_CLS) ? 1.f : 0.f;
        colA[min(b3, 18u) << 6] += (b3 < K_CLS) ? 1.f : 0.f;
      }
    };
    sweepC();
    asm volatile("" ::: "memory");
    sweepC();

    float acc[K_CLS];
#pragma unroll
    for (int k = 0; k < K_CLS; ++k) acc[k] = colA[k << 6];
#pragma unroll
    for (int k = 0; k < K_CLS; ++k) {
      float s = acc[k];
#pragma unroll
      for (int m = 1; m < 64; m <<= 1) s += __shfl_xor(s, m, 64);
      acc[k] = s;
    }
#pragma unroll
    for (int k = 0; k < K_CLS; ++k)
      if (lane == k) s_w[w][k] = acc[k];
    __syncthreads();
    if (t < K_CLS) {
      const int slot = idx;
      ws[OFF_PCNT + slot * 20 + t] =
          0.5f * (s_w[0][t] + s_w[1][t] + s_w[2][t] + s_w[3][t]);
    }
  }
}

// ---- Reduce: 627 one-wave blocks, lane = slot -----------------------------
__global__ __launch_bounds__(64) void k_reduce(float* __restrict__ ws)
{
  const int o = blockIdx.x;            // 0..626
  const int lane = threadIdx.x;        // 0..63 = slot
  float a;
  if (o < C_CH * K_CLS) {
    const int ch = o / K_CLS, k = o - ch * K_CLS;
    a = ws[OFF_PSUM + ch * (64 * 20) + lane * 20 + k];
  } else {
    a = ws[OFF_PCNT + lane * 20 + (o - C_CH * K_CLS)];
  }
#pragma unroll
  for (int m = 1; m < 64; m <<= 1) a += __shfl_xor(a, m, 64);
  if (lane == 0) ws[OFF_RED + o] = a;
}

// ---- Pass 2 (2-sweep diagnostic): channel-outer + bpermute ctr gather -----
__global__ __launch_bounds__(256) void k_var(
    const float* __restrict__ pred, const int* __restrict__ tgt,
    float* __restrict__ ws)
{
  __shared__ float s_red[640];
  __shared__ float s_w[4][40];
  const int t = threadIdx.x;
  const int w = t >> 6;
  const int lane = t & 63;

  for (int i = t; i < 627; i += 256) s_red[i] = ws[OFF_RED + i];
  __syncthreads();

  const float invc = (lane < K_CLS) ? 1.f / fmaxf(s_red[608 + lane], 1.f) : 0.f;
  float ctrreg[C_CH];
  float c2reg = 0.f;
#pragma unroll
  for (int c = 0; c < C_CH; ++c) {
    ctrreg[c] = (lane < K_CLS) ? s_red[c * K_CLS + lane] * invc : 0.f;
    c2reg = fmaf(ctrreg[c], ctrreg[c], c2reg);
  }

  const int bpx = blockIdx.x * 2048;
  const int n_idx = bpx >> HW_SHIFT;
  const int hw0 = bpx & (HW_SIZE - 1);

  const int* tb = tgt + (((size_t)n_idx) << HW_SHIFT) + hw0;
  const int4 ca = *reinterpret_cast<const int4*>(tb + t * 4);
  const int4 cb = *reinterpret_cast<const int4*>(tb + 1024 + t * 4);
  const int cls[8] = {ca.x, ca.y, ca.z, ca.w, cb.x, cb.y, cb.z, cb.w};
  int idx8[8];
#pragma unroll
  for (int j = 0; j < 8; ++j)
    idx8[j] = min((unsigned)cls[j], 19u) << 2;   // invalid -> lane 19 (ctr=0)

  float nrm[8] = {0.f,0.f,0.f,0.f,0.f,0.f,0.f,0.f};
  float dot[8] = {0.f,0.f,0.f,0.f,0.f,0.f,0.f,0.f};

  auto sweepV = [&]() {
#pragma unroll
    for (int c = 0; c < C_CH; ++c) {
      const float* cp = pred + (((size_t)(n_idx * C_CH + c)) << HW_SHIFT) + hw0;
      const float4 xa = *reinterpret_cast<const float4*>(cp + t * 4);
      const float4 xb = *reinterpret_cast<const float4*>(cp + 1024 + t * 4);
      const float x[8] = {xa.x, xa.y, xa.z, xa.w, xb.x, xb.y, xb.z, xb.w};
#pragma unroll
      for (int j = 0; j < 8; ++j) {
        const float cv = bperm(ctrreg[c], idx8[j]);
        nrm[j] = fmaf(x[j], x[j], nrm[j]);
        dot[j] = fmaf(x[j], cv, dot[j]);
      }
    }
  };
  sweepV();
  asm volatile("" ::: "memory");   // forbid load-CSE: sweep 2 must re-read
  sweepV();

  float acc_sq[K_CLS], acc_pos[K_CLS];
#pragma unroll
  for (int k = 0; k < K_CLS; ++k) { acc_sq[k] = 0.f; acc_pos[k] = 0.f; }
#pragma unroll
  for (int j = 0; j < 8; ++j) {
    const float c2j = bperm(c2reg, idx8[j]);
    const float nv = 0.5f * nrm[j];
    const float dv = 0.5f * dot[j];
    const float d2 = fmaxf(nv - 2.f * dv + c2j, 0.f);
    const float r = sqrtf(d2 + EPSF) - THEA_F;
    const bool act = ((unsigned)cls[j] < K_CLS) && (r > 0.f);
    const float rr = act ? r * r : 0.f;
    const float pp = act ? 1.f : 0.f;
    const int sc = min((unsigned)cls[j], 18u);
#pragma unroll
    for (int k = 0; k < K_CLS; ++k) {
      const bool b = (sc == k);
      acc_sq[k]  += b ? rr : 0.f;
      acc_pos[k] += b ? pp : 0.f;
    }
  }

#pragma unroll
  for (int k = 0; k < K_CLS; ++k) {
    float a = acc_sq[k], b = acc_pos[k];
#pragma unroll
    for (int m = 1; m < 64; m <<= 1) {
      a += __shfl_xor(a, m, 64);
      b += __shfl_xor(b, m, 64);
    }
    acc_sq[k] = a; acc_pos[k] = b;
  }
#pragma unroll
  for (int k = 0; k < K_CLS; ++k)
    if (lane == k) { s_w[w][k] = acc_sq[k]; s_w[w][20 + k] = acc_pos[k]; }
  __syncthreads();
  if (t < K_CLS) {
    float* vp = ws + OFF_VPART + (size_t)blockIdx.x * 64;
    vp[t]         = s_w[0][t] + s_w[1][t] + s_w[2][t] + s_w[3][t];
    vp[K_CLS + t] = s_w[0][20 + t] + s_w[1][20 + t] + s_w[2][20 + t] + s_w[3][20 + t];
  }
}

// ---- Pre-reduce sq/pos: 38 blocks over 1024 partials ----------------------
__global__ __launch_bounds__(256) void k_vred(float* __restrict__ ws)
{
  const int o = blockIdx.x;            // 0..37
  const int t = threadIdx.x;
  float a = 0.f;
#pragma unroll
  for (int r = 0; r < 4; ++r)
    a += ws[OFF_VPART + (size_t)(t + r * 256) * 64 + o];
#pragma unroll
  for (int m = 1; m < 64; m <<= 1) a += __shfl_xor(a, m, 64);
  __shared__ float s[4];
  if ((t & 63) == 0) s[t >> 6] = a;
  __syncthreads();
  if (t == 0) ws[OFF_VRED + o] = s[0] + s[1] + s[2] + s[3];
}

// ---- Finalize -------------------------------------------------------------
__global__ __launch_bounds__(1024) void k_final(
    float* __restrict__ ws, float* __restrict__ out)
{
  __shared__ float s_ctr[C_CH * K_CLS];
  __shared__ float s_valid[K_CLS];
  __shared__ float s_red[3];
  __shared__ float s_ncls;
  const int t = threadIdx.x;
  if (t < 3) s_red[t] = 0.f;
  if (t < K_CLS) s_valid[t] = (ws[OFF_RED + C_CH * K_CLS + t] > MIN_PIX) ? 1.f : 0.f;
  for (int i = t; i < C_CH * K_CLS; i += 1024) {
    const int k = i % K_CLS;
    s_ctr[i] = ws[OFF_RED + i] / fmaxf(ws[OFF_RED + C_CH * K_CLS + k], 1.f);
  }
  __syncthreads();

  if (t == 0) {
    float n = 0.f;
    for (int k = 0; k < K_CLS; ++k) n += s_valid[k];
    s_ncls = fmaxf(n, 1.f);
  }
  if (t < K_CLS && s_valid[t] > 0.f) {
    const float sq  = ws[OFF_VRED + t];
    const float pos = ws[OFF_VRED + K_CLS + t];
    atomAddF(&s_red[0], sq / fmaxf(pos, 1.f));
    float nn = 0.f;
#pragma unroll
    for (int ch = 0; ch < C_CH; ++ch) {
      const float cv = s_ctr[ch * K_CLS + t];
      nn = fmaf(cv, cv, nn);
    }
    atomAddF(&s_red[2], sqrtf(nn + EPSF));
  }
  if (t < K_CLS * K_CLS) {
    const int a = t / K_CLS, b = t - (t / K_CLS) * K_CLS;
    if (a != b && s_valid[a] > 0.f && s_valid[b] > 0.f) {
      float dd = 0.f;
#pragma unroll
      for (int ch = 0; ch < C_CH; ++ch) {
        const float df = s_ctr[ch * K_CLS + a] - s_ctr[ch * K_CLS + b];
        dd = fmaf(df, df, dd);
      }
      const float dist = sqrtf(dd + EPSF);
      const float d = fmaxf(TWO_DELTA - dist, 0.f);
      if (d > 0.f) atomAddF(&s_red[1], d * d);
    }
  }
  __syncthreads();
  if (t == 0) {
    const float n = s_ncls;
    out[0] = s_red[0] / n
           + s_red[1] / fmaxf(n * (n - 1.f), 1.f)
           + 0.001f * s_red[2] / n;
  }
}

extern "C" void kernel_launch(void* const* d_in, const int* in_sizes, int n_in,
                              void* d_out, int out_size, void* d_ws, size_t ws_size,
                              hipStream_t stream) {
  const float* pred = (const float*)d_in[0];
  const int*   tgt  = (const int*)d_in[1];
  float* ws  = (float*)d_ws;
  float* out = (float*)d_out;
  const int P = in_sizes[1];            // n*h*w = 2097152

  k_pack  <<<P / 1024, 256, 0, stream>>>(tgt, ws);         // 2MB u8 map
  k_accum <<<2048 + 64, 256, 0, stream>>>(pred, ws);       // 2-sweep diagnostic
  k_reduce<<<C_CH * K_CLS + K_CLS, 64, 0, stream>>>(ws);   // 627 one-wave blocks
  k_var   <<<P / 2048, 256, 0, stream>>>(pred, tgt, ws);   // 2-sweep diagnostic
  k_vred  <<<2 * K_CLS, 256, 0, stream>>>(ws);             // 38 blocks
  k_final <<<1, 1024, 0, stream>>>(ws, out);
}

// Round 16
// 418.642 us; speedup vs baseline: 1.3764x; 1.3764x over previous
//
#include <hip/hip_runtime.h>

// HNM discriminative loss, MI355X — R19 (= R18 with compile fix).
// predict (4,32,512,1024) f32, target (4,512,1024) i32 -> scalar f32.
// R18's NT-load experiment never ran: __builtin_nontemporal_load rejects
// HIP_vector_type<float,4>*. Fix: load via clang ext_vector_type(4) float
// (same 16B layout), bit-cast to float4. Single variable preserved:
// NT loads on pred (single-touch per kernel) in both hot kernels; map/tgt
// keep normal loads. Else byte-identical to R16.
// R17 evidence: cold-read service ~1.7-2.2 TB/s is the limiter (warm
// sweeps ~10-48us; VALU/DS/occupancy all exonerated by counters).
// Pre-reg: (a) theory right: total 444 -> ~340-380; (b) unchanged:
// R20 cuts pass-2 bytes (fp16 stash); (c) worse: revert nt.

#define K_CLS 19
#define C_CH 32
#define HW_SHIFT 19            // H*W = 512*1024 = 2^19
#define HW_SIZE (1 << HW_SHIFT)
#define EPSF 1e-12f
#define THEA_F 0.5f
#define TWO_DELTA 3.0f
#define MIN_PIX 20.0f

// ---- ws float layout ------------------------------------------------------
#define OFF_PSUM 0                       // [ch][64 slots][20] = 40960
#define OFF_PCNT 40960                   // [64 slots][20] = 1280
#define OFF_RED  42240                   // 608 sums + 19 counts (pad 640)
#define OFF_VRED 42880                   // 38 reduced sq/pos (pad 64)
#define OFF_VPART 42944                  // [1024 blk][64]: 19 sq + 19 pos
#define OFF_MAP  108480                  // u8 class map: 2MB = 524288 floats
#define WS_FLOATS (OFF_MAP + 524288)

typedef float __attribute__((ext_vector_type(4))) fx4;   // native vec for NT builtin

__device__ __forceinline__ void atomAddF(float* p, float v) {
  unsafeAtomicAdd(p, v);       // cold paths only
}

__device__ __forceinline__ float bperm(float v, int byteidx) {
  return __int_as_float(__builtin_amdgcn_ds_bpermute(byteidx, __float_as_int(v)));
}

__device__ __forceinline__ float4 ldnt4(const float* p) {
  const fx4 v = __builtin_nontemporal_load(reinterpret_cast<const fx4*>(p));
  return make_float4(v.x, v.y, v.z, v.w);
}

// ---- Pack: tgt int32 -> u8 class map (2MB). ~3us. -------------------------
__global__ __launch_bounds__(256) void k_pack(
    const int* __restrict__ tgt, float* __restrict__ ws)
{
  const int i = blockIdx.x * 256 + threadIdx.x;   // word index, 4 px each
  const int4 c = *reinterpret_cast<const int4*>(tgt + (size_t)i * 4);
  const unsigned u = (unsigned)(c.x & 255) | ((unsigned)(c.y & 255) << 8)
                   | ((unsigned)(c.z & 255) << 16) | ((unsigned)(c.w & 255) << 24);
  reinterpret_cast<unsigned*>(ws + OFF_MAP)[i] = u;
}

// ---- Pass 1: bank-per-lane histogram, NT pred reads -----------------------
__global__ __launch_bounds__(256) void k_accum(
    const float* __restrict__ pred, float* __restrict__ ws)
{
  __shared__ float sA[4][K_CLS][64];            // 19456 B -> 8 blocks/CU
  __shared__ float s_w[4][20];
  const int t = threadIdx.x;
  const int w = t >> 6;
  const int lane = t & 63;
  const unsigned* umap = reinterpret_cast<const unsigned*>(ws + OFF_MAP);
  float* colA = &sA[w][0][lane];                // colA[k<<6] = bin k, bank l%32
#pragma unroll
  for (int k = 0; k < K_CLS; ++k) colA[k << 6] = 0.f;

  if (blockIdx.x < 2048) {
    const int plane = blockIdx.x >> 4;       // 0..127
    const int slab  = blockIdx.x & 15;       // 0..15
    const int n_idx = plane >> 5;
    const int ch    = plane & 31;
    const float* pbase = pred + (((size_t)plane) << HW_SHIFT) + ((size_t)slab << 15);
    const int mbase = ((n_idx << HW_SHIFT) + (slab << 15)) >> 2;

    float4 vA = ldnt4(pbase + t * 4);
    unsigned mA = umap[mbase + t];
#pragma unroll 1
    for (int it = 0; it < 32; ++it) {
      float4 vB; unsigned mB;
      if (it + 1 < 32) {
        vB = ldnt4(pbase + (it + 1) * 1024 + t * 4);
        mB = umap[mbase + (it + 1) * 256 + t];
      }
      const unsigned b0 = mA & 255u, b1 = (mA >> 8) & 255u;
      const unsigned b2 = (mA >> 16) & 255u, b3 = mA >> 24;
      const int   k0 = min(b0, 18u), k1 = min(b1, 18u);
      const int   k2 = min(b2, 18u), k3 = min(b3, 18u);
      const float v0 = (b0 < K_CLS) ? vA.x : 0.f;
      const float v1 = (b1 < K_CLS) ? vA.y : 0.f;
      const float v2 = (b2 < K_CLS) ? vA.z : 0.f;
      const float v3 = (b3 < K_CLS) ? vA.w : 0.f;
      colA[k0 << 6] += v0;
      colA[k1 << 6] += v1;
      colA[k2 << 6] += v2;
      colA[k3 << 6] += v3;
      vA = vB; mA = mB;
    }

    float acc[K_CLS];
#pragma unroll
    for (int k = 0; k < K_CLS; ++k) acc[k] = colA[k << 6];
#pragma unroll
    for (int k = 0; k < K_CLS; ++k) {
      float s = acc[k];
#pragma unroll
      for (int m = 1; m < 64; m <<= 1) s += __shfl_xor(s, m, 64);
      acc[k] = s;
    }
#pragma unroll
    for (int k = 0; k < K_CLS; ++k)
      if (lane == k) s_w[w][k] = acc[k];
    __syncthreads();
    if (t < K_CLS) {
      const int slot = n_idx * 16 + slab;
      ws[OFF_PSUM + ch * (64 * 20) + slot * 20 + t] =
          s_w[0][t] + s_w[1][t] + s_w[2][t] + s_w[3][t];
    }
  } else {
    const int idx = blockIdx.x - 2048;       // 0..63
    const int mbase = idx << 13;             // (idx*32768)/4

#pragma unroll 1
    for (int it = 0; it < 32; ++it) {
      const unsigned m = umap[mbase + it * 256 + t];
      const unsigned b0 = m & 255u, b1 = (m >> 8) & 255u;
      const unsigned b2 = (m >> 16) & 255u, b3 = m >> 24;
      colA[min(b0, 18u) << 6] += (b0 < K_CLS) ? 1.f : 0.f;
      colA[min(b1, 18u) << 6] += (b1 < K_CLS) ? 1.f : 0.f;
      colA[min(b2, 18u) << 6] += (b2 < K_CLS) ? 1.f : 0.f;
      colA[min(b3, 18u) << 6] += (b3 < K_CLS) ? 1.f : 0.f;
    }

    float acc[K_CLS];
#pragma unroll
    for (int k = 0; k < K_CLS; ++k) acc[k] = colA[k << 6];
#pragma unroll
    for (int k = 0; k < K_CLS; ++k) {
      float s = acc[k];
#pragma unroll
      for (int m = 1; m < 64; m <<= 1) s += __shfl_xor(s, m, 64);
      acc[k] = s;
    }
#pragma unroll
    for (int k = 0; k < K_CLS; ++k)
      if (lane == k) s_w[w][k] = acc[k];
    __syncthreads();
    if (t < K_CLS) {
      const int slot = idx;
      ws[OFF_PCNT + slot * 20 + t] = s_w[0][t] + s_w[1][t] + s_w[2][t] + s_w[3][t];
    }
  }
}

// ---- Reduce: 627 one-wave blocks, lane = slot -----------------------------
__global__ __launch_bounds__(64) void k_reduce(float* __restrict__ ws)
{
  const int o = blockIdx.x;            // 0..626
  const int lane = threadIdx.x;        // 0..63 = slot
  float a;
  if (o < C_CH * K_CLS) {
    const int ch = o / K_CLS, k = o - ch * K_CLS;
    a = ws[OFF_PSUM + ch * (64 * 20) + lane * 20 + k];
  } else {
    a = ws[OFF_PCNT + lane * 20 + (o - C_CH * K_CLS)];
  }
#pragma unroll
  for (int m = 1; m < 64; m <<= 1) a += __shfl_xor(a, m, 64);
  if (lane == 0) ws[OFF_RED + o] = a;
}

// ---- Pass 2: channel-outer + bpermute ctr gather, NT pred reads -----------
__global__ __launch_bounds__(256) void k_var(
    const float* __restrict__ pred, const int* __restrict__ tgt,
    float* __restrict__ ws)
{
  __shared__ float s_red[640];
  __shared__ float s_w[4][40];
  const int t = threadIdx.x;
  const int w = t >> 6;
  const int lane = t & 63;

  for (int i = t; i < 627; i += 256) s_red[i] = ws[OFF_RED + i];
  __syncthreads();

  const float invc = (lane < K_CLS) ? 1.f / fmaxf(s_red[608 + lane], 1.f) : 0.f;
  float ctrreg[C_CH];
  float c2reg = 0.f;
#pragma unroll
  for (int c = 0; c < C_CH; ++c) {
    ctrreg[c] = (lane < K_CLS) ? s_red[c * K_CLS + lane] * invc : 0.f;
    c2reg = fmaf(ctrreg[c], ctrreg[c], c2reg);
  }

  const int bpx = blockIdx.x * 2048;
  const int n_idx = bpx >> HW_SHIFT;
  const int hw0 = bpx & (HW_SIZE - 1);

  const int* tb = tgt + (((size_t)n_idx) << HW_SHIFT) + hw0;
  const int4 ca = *reinterpret_cast<const int4*>(tb + t * 4);
  const int4 cb = *reinterpret_cast<const int4*>(tb + 1024 + t * 4);
  const int cls[8] = {ca.x, ca.y, ca.z, ca.w, cb.x, cb.y, cb.z, cb.w};
  int idx8[8];
#pragma unroll
  for (int j = 0; j < 8; ++j)
    idx8[j] = min((unsigned)cls[j], 19u) << 2;   // invalid -> lane 19 (ctr=0)

  float nrm[8] = {0.f,0.f,0.f,0.f,0.f,0.f,0.f,0.f};
  float dot[8] = {0.f,0.f,0.f,0.f,0.f,0.f,0.f,0.f};
#pragma unroll
  for (int c = 0; c < C_CH; ++c) {
    const float* cp = pred + (((size_t)(n_idx * C_CH + c)) << HW_SHIFT) + hw0;
    const float4 xa = ldnt4(cp + t * 4);
    const float4 xb = ldnt4(cp + 1024 + t * 4);
    const float x[8] = {xa.x, xa.y, xa.z, xa.w, xb.x, xb.y, xb.z, xb.w};
#pragma unroll
    for (int j = 0; j < 8; ++j) {
      const float cv = bperm(ctrreg[c], idx8[j]);
      nrm[j] = fmaf(x[j], x[j], nrm[j]);
      dot[j] = fmaf(x[j], cv, dot[j]);
    }
  }

  float acc_sq[K_CLS], acc_pos[K_CLS];
#pragma unroll
  for (int k = 0; k < K_CLS; ++k) { acc_sq[k] = 0.f; acc_pos[k] = 0.f; }
#pragma unroll
  for (int j = 0; j < 8; ++j) {
    const float c2j = bperm(c2reg, idx8[j]);
    const float d2 = fmaxf(nrm[j] - 2.f * dot[j] + c2j, 0.f);
    const float r = sqrtf(d2 + EPSF) - THEA_F;
    const bool act = ((unsigned)cls[j] < K_CLS) && (r > 0.f);
    const float rr = act ? r * r : 0.f;
    const float pp = act ? 1.f : 0.f;
    const int sc = min((unsigned)cls[j], 18u);
#pragma unroll
    for (int k = 0; k < K_CLS; ++k) {
      const bool b = (sc == k);
      acc_sq[k]  += b ? rr : 0.f;
      acc_pos[k] += b ? pp : 0.f;
    }
  }

#pragma unroll
  for (int k = 0; k < K_CLS; ++k) {
    float a = acc_sq[k], b = acc_pos[k];
#pragma unroll
    for (int m = 1; m < 64; m <<= 1) {
      a += __shfl_xor(a, m, 64);
      b += __shfl_xor(b, m, 64);
    }
    acc_sq[k] = a; acc_pos[k] = b;
  }
#pragma unroll
  for (int k = 0; k < K_CLS; ++k)
    if (lane == k) { s_w[w][k] = acc_sq[k]; s_w[w][20 + k] = acc_pos[k]; }
  __syncthreads();
  if (t < K_CLS) {
    float* vp = ws + OFF_VPART + (size_t)blockIdx.x * 64;
    vp[t]         = s_w[0][t] + s_w[1][t] + s_w[2][t] + s_w[3][t];
    vp[K_CLS + t] = s_w[0][20 + t] + s_w[1][20 + t] + s_w[2][20 + t] + s_w[3][20 + t];
  }
}

// ---- Pre-reduce sq/pos: 38 blocks over 1024 partials ----------------------
__global__ __launch_bounds__(256) void k_vred(float* __restrict__ ws)
{
  const int o = blockIdx.x;            // 0..37
  const int t = threadIdx.x;
  float a = 0.f;
#pragma unroll
  for (int r = 0; r < 4; ++r)
    a += ws[OFF_VPART + (size_t)(t + r * 256) * 64 + o];
#pragma unroll
  for (int m = 1; m < 64; m <<= 1) a += __shfl_xor(a, m, 64);
  __shared__ float s[4];
  if ((t & 63) == 0) s[t >> 6] = a;
  __syncthreads();
  if (t == 0) ws[OFF_VRED + o] = s[0] + s[1] + s[2] + s[3];
}

// ---- Finalize -------------------------------------------------------------
__global__ __launch_bounds__(1024) void k_final(
    float* __restrict__ ws, float* __restrict__ out)
{
  __shared__ float s_ctr[C_CH * K_CLS];
  __shared__ float s_valid[K_CLS];
  __shared__ float s_red[3];
  __shared__ float s_ncls;
  const int t = threadIdx.x;
  if (t < 3) s_red[t] = 0.f;
  if (t < K_CLS) s_valid[t] = (ws[OFF_RED + C_CH * K_CLS + t] > MIN_PIX) ? 1.f : 0.f;
  for (int i = t; i < C_CH * K_CLS; i += 1024) {
    const int k = i % K_CLS;
    s_ctr[i] = ws[OFF_RED + i] / fmaxf(ws[OFF_RED + C_CH * K_CLS + k], 1.f);
  }
  __syncthreads();

  if (t == 0) {
    float n = 0.f;
    for (int k = 0; k < K_CLS; ++k) n += s_valid[k];
    s_ncls = fmaxf(n, 1.f);
  }
  if (t < K_CLS && s_valid[t] > 0.f) {
    const float sq  = ws[OFF_VRED + t];
    const float pos = ws[OFF_VRED + K_CLS + t];
    atomAddF(&s_red[0], sq / fmaxf(pos, 1.f));
    float nn = 0.f;
#pragma unroll
    for (int ch = 0; ch < C_CH; ++ch) {
      const float cv = s_ctr[ch * K_CLS + t];
      nn = fmaf(cv, cv, nn);
    }
    atomAddF(&s_red[2], sqrtf(nn + EPSF));
  }
  if (t < K_CLS * K_CLS) {
    const int a = t / K_CLS, b = t - (t / K_CLS) * K_CLS;
    if (a != b && s_valid[a] > 0.f && s_valid[b] > 0.f) {
      float dd = 0.f;
#pragma unroll
      for (int ch = 0; ch < C_CH; ++ch) {
        const float df = s_ctr[ch * K_CLS + a] - s_ctr[ch * K_CLS + b];
        dd = fmaf(df, df, dd);
      }
      const float dist = sqrtf(dd + EPSF);
      const float d = fmaxf(TWO_DELTA - dist, 0.f);
      if (d > 0.f) atomAddF(&s_red[1], d * d);
    }
  }
  __syncthreads();
  if (t == 0) {
    const float n = s_ncls;
    out[0] = s_red[0] / n
           + s_red[1] / fmaxf(n * (n - 1.f), 1.f)
           + 0.001f * s_red[2] / n;
  }
}

extern "C" void kernel_launch(void* const* d_in, const int* in_sizes, int n_in,
                              void* d_out, int out_size, void* d_ws, size_t ws_size,
                              hipStream_t stream) {
  const float* pred = (const float*)d_in[0];
  const int*   tgt  = (const int*)d_in[1];
  float* ws  = (float*)d_ws;
  float* out = (float*)d_out;
  const int P = in_sizes[1];            // n*h*w = 2097152

  k_pack  <<<P / 1024, 256, 0, stream>>>(tgt, ws);         // 2MB u8 map
  k_accum <<<2048 + 64, 256, 0, stream>>>(pred, ws);       // NT pred reads
  k_reduce<<<C_CH * K_CLS + K_CLS, 64, 0, stream>>>(ws);   // 627 one-wave blocks
  k_var   <<<P / 2048, 256, 0, stream>>>(pred, tgt, ws);   // NT pred reads
  k_vred  <<<2 * K_CLS, 256, 0, stream>>>(ws);             // 38 blocks
  k_final <<<1, 1024, 0, stream>>>(ws, out);
}